// Round 7
// baseline (1272.775 us; speedup 1.0000x reference)
//
#include <hip/hip_runtime.h>

typedef __attribute__((ext_vector_type(8))) short s8v;
typedef __attribute__((ext_vector_type(4))) float f4v;

#define LOG2E 1.44269504088896340736f

__device__ __forceinline__ unsigned short f2bf(float f) {
    unsigned int x = __float_as_uint(f);
    return (unsigned short)((x + 0x7fffu + ((x >> 16) & 1u)) >> 16);
}
__device__ __forceinline__ s8v ld8(const unsigned short* p) {
    return *(const s8v*)p;
}
__device__ __forceinline__ s8v cvt8(const float* p) {
    f4v lo = *(const f4v*)p, hi = *(const f4v*)(p + 4);
    s8v r;
    r[0] = (short)f2bf(lo[0]); r[1] = (short)f2bf(lo[1]);
    r[2] = (short)f2bf(lo[2]); r[3] = (short)f2bf(lo[3]);
    r[4] = (short)f2bf(hi[0]); r[5] = (short)f2bf(hi[1]);
    r[6] = (short)f2bf(hi[2]); r[7] = (short)f2bf(hi[3]);
    return r;
}

// ------- W transpose + fp32->bf16: Wt[n][k] = bf16(W[k][n]), 1024x1024 -----
__global__ __launch_bounds__(256) void transpose_w(
    const float* __restrict__ W, unsigned short* __restrict__ Wt)
{
    __shared__ float tile[32][33];
    int tx = threadIdx.x, ty = threadIdx.y;
    int x = blockIdx.x * 32 + tx;
#pragma unroll
    for (int i = 0; i < 4; i++) {
        int y = blockIdx.y * 32 + ty + i * 8;
        tile[ty + i * 8][tx] = W[y * 1024 + x];
    }
    __syncthreads();
    int x2 = blockIdx.y * 32 + tx;
#pragma unroll
    for (int i = 0; i < 4; i++) {
        int y2 = blockIdx.x * 32 + ty + i * 8;
        Wt[y2 * 1024 + x2] = f2bf(tile[tx][ty + i * 8]);
    }
}

// ------- GEMM: out = A[8192,1024] @ Bt^T + bias ----------------------------
// Bt is [N=1024][K=1024] bf16. 64x64 block tile, 4 waves, wave = 16-row strip
// x 64 cols. AF32: A fp32 (convert in-register) else bf16.
// mode 0: FP32 store [row][col] (the final output!)
// mode 1: bf16 Q/K store [b,h,l,d].  mode 2: bf16 V^T store [b,h,d,l].
template<int AF32>
__global__ __launch_bounds__(256) void gemm_bt(
    const void* __restrict__ Av,
    const unsigned short* __restrict__ Bt,
    const float* __restrict__ bias,
    void* __restrict__ outv, int mode)
{
    int w = threadIdx.x >> 6, lane = threadIdx.x & 63;
    int quad = lane >> 4, l15 = lane & 15;
    int m0 = blockIdx.y * 64 + w * 16;
    int n0 = blockIdx.x * 64;

    f4v acc[4];
#pragma unroll
    for (int t = 0; t < 4; t++) { f4v z = {0.f, 0.f, 0.f, 0.f}; acc[t] = z; }

    for (int k0 = 0; k0 < 1024; k0 += 32) {
        s8v a;
        if (AF32) a = cvt8((const float*)Av + (m0 + l15) * 1024 + quad * 8 + k0);
        else      a = ld8((const unsigned short*)Av + (m0 + l15) * 1024 + quad * 8 + k0);
#pragma unroll
        for (int t = 0; t < 4; t++) {
            s8v b = ld8(Bt + (n0 + t * 16 + l15) * 1024 + quad * 8 + k0);
            acc[t] = __builtin_amdgcn_mfma_f32_16x16x32_bf16(a, b, acc[t], 0, 0, 0);
        }
    }

#pragma unroll
    for (int t = 0; t < 4; t++) {
        int col = n0 + t * 16 + l15;
        float bvf = bias[col];
#pragma unroll
        for (int r = 0; r < 4; r++) {
            int row = m0 + quad * 4 + r;
            float v = acc[t][r] + bvf;
            if (mode == 0) {
                ((float*)outv)[row * 1024 + col] = v;      // FP32 final output
            } else {
                unsigned short* out = (unsigned short*)outv;
                int b = row >> 11, l = row & 2047;
                int h = col >> 6, d = col & 63;
                if (mode == 1) out[((b * 16 + h) * 2048 + l) * 64 + d] = f2bf(v);
                else           out[((b * 16 + h) * 64 + d) * 2048 + l] = f2bf(v);
            }
        }
    }
}

// ------- Flash attention (causal) ------------------------------------------
// Q,K: [B,H,L,64] bf16.  Vt: [B,H,64,L] bf16.  O: [B*L,1024] bf16.
__global__ __launch_bounds__(256) void attn_kernel(
    const unsigned short* __restrict__ Q,
    const unsigned short* __restrict__ K,
    const unsigned short* __restrict__ Vt,
    unsigned short* __restrict__ O)
{
    __shared__ __align__(16) unsigned short Pb[4][16][64];
    int w = threadIdx.x >> 6, lane = threadIdx.x & 63;
    int quad = lane >> 4, l15 = lane & 15;
    int qt = blockIdx.x, h = blockIdx.y, b = blockIdx.z;
    int bh = b * 16 + h;
    int m0 = qt * 64 + w * 16;

    const unsigned short* qb = Q + (bh * 2048 + m0 + l15) * 64 + quad * 8;
    s8v aq0 = ld8(qb);
    s8v aq1 = ld8(qb + 32);

    float mrun[4], lrun[4];
    f4v oacc[4];
#pragma unroll
    for (int r = 0; r < 4; r++) { mrun[r] = -1e30f; lrun[r] = 0.f; }
#pragma unroll
    for (int t = 0; t < 4; t++) { f4v z = {0.f, 0.f, 0.f, 0.f}; oacc[t] = z; }

    const float sscale = 0.125f * LOG2E;   // softmax in log2 domain

    for (int kt = 0; kt <= qt; kt++) {
        f4v sacc[4];
#pragma unroll
        for (int t = 0; t < 4; t++) { f4v z = {0.f, 0.f, 0.f, 0.f}; sacc[t] = z; }
        const unsigned short* kb = K + (bh * 2048 + kt * 64 + l15) * 64 + quad * 8;
#pragma unroll
        for (int t = 0; t < 4; t++) {
            s8v b0 = ld8(kb + t * 16 * 64);
            s8v b1 = ld8(kb + t * 16 * 64 + 32);
            sacc[t] = __builtin_amdgcn_mfma_f32_16x16x32_bf16(aq0, b0, sacc[t], 0, 0, 0);
            sacc[t] = __builtin_amdgcn_mfma_f32_16x16x32_bf16(aq1, b1, sacc[t], 0, 0, 0);
        }

#pragma unroll
        for (int r = 0; r < 4; r++) {
            int row = m0 + quad * 4 + r;
            float sv[4];
            float mx = -1e30f;
#pragma unroll
            for (int t = 0; t < 4; t++) {
                int key = kt * 64 + t * 16 + l15;
                float s = sacc[t][r] * sscale;
                if (key > row) s = -1e30f;
                sv[t] = s;
                mx = fmaxf(mx, s);
            }
#pragma unroll
            for (int off = 1; off < 16; off <<= 1)
                mx = fmaxf(mx, __shfl_xor(mx, off));
            float mnew = fmaxf(mrun[r], mx);
            float alpha = exp2f(mrun[r] - mnew);
            float rs = 0.f;
#pragma unroll
            for (int t = 0; t < 4; t++) {
                float p = exp2f(sv[t] - mnew);
                sacc[t][r] = p;
                rs += p;
            }
#pragma unroll
            for (int off = 1; off < 16; off <<= 1)
                rs += __shfl_xor(rs, off);
            lrun[r] = lrun[r] * alpha + rs;
            mrun[r] = mnew;
#pragma unroll
            for (int t = 0; t < 4; t++) oacc[t][r] *= alpha;
        }

        __syncthreads();
#pragma unroll
        for (int t = 0; t < 4; t++)
#pragma unroll
            for (int r = 0; r < 4; r++)
                Pb[w][quad * 4 + r][t * 16 + l15] = f2bf(sacc[t][r]);
        __syncthreads();

        const unsigned short* vb = Vt + (bh * 64 + l15) * 2048 + kt * 64 + quad * 8;
#pragma unroll
        for (int c = 0; c < 2; c++) {
            s8v apf = *(const s8v*)&Pb[w][l15][c * 32 + quad * 8];
#pragma unroll
            for (int t2 = 0; t2 < 4; t2++) {
                s8v bvv = ld8(vb + t2 * 16 * 2048 + c * 32);
                oacc[t2] = __builtin_amdgcn_mfma_f32_16x16x32_bf16(apf, bvv, oacc[t2], 0, 0, 0);
            }
        }
    }

#pragma unroll
    for (int r = 0; r < 4; r++) {
        float inv = 1.f / lrun[r];
        int l = m0 + quad * 4 + r;
#pragma unroll
        for (int t2 = 0; t2 < 4; t2++) {
            O[(b * 2048 + l) * 1024 + h * 64 + t2 * 16 + l15] = f2bf(oacc[t2][r] * inv);
        }
    }
}

// ------- launch ------------------------------------------------------------
extern "C" void kernel_launch(void* const* d_in, const int* in_sizes, int n_in,
                              void* d_out, int out_size, void* d_ws, size_t ws_size,
                              hipStream_t stream)
{
    const float* queries = (const float*)d_in[0];
    const float* keys    = (const float*)d_in[1];
    const float* values  = (const float*)d_in[2];
    const float* Wq = (const float*)d_in[3];
    const float* bq = (const float*)d_in[4];
    const float* Wk = (const float*)d_in[5];
    const float* bk = (const float*)d_in[6];
    const float* Wv = (const float*)d_in[7];
    const float* bv = (const float*)d_in[8];
    const float* Wo = (const float*)d_in[9];
    const float* bo = (const float*)d_in[10];

    // ws (bf16 elems): 4x1M W^T + 3x8M Q/K/V^T + 8M ow = 72 MB
    unsigned short* ws = (unsigned short*)d_ws;
    const size_t M1 = 1u << 20, M8 = 8u << 20;
    unsigned short* WqT = ws;
    unsigned short* WkT = ws + 1 * M1;
    unsigned short* WvT = ws + 2 * M1;
    unsigned short* WoT = ws + 3 * M1;
    unsigned short* qw  = ws + 4 * M1;      // [B,H,L,64]
    unsigned short* kw  = qw + M8;          // [B,H,L,64]
    unsigned short* vtw = kw + M8;          // [B,H,64,L]
    unsigned short* ow  = vtw + M8;         // [B*L,1024]

    dim3 tb(32, 8), tg(32, 32);
    transpose_w<<<tg, tb, 0, stream>>>(Wq, WqT);
    transpose_w<<<tg, tb, 0, stream>>>(Wk, WkT);
    transpose_w<<<tg, tb, 0, stream>>>(Wv, WvT);
    transpose_w<<<tg, tb, 0, stream>>>(Wo, WoT);

    dim3 gg(16, 128);
    gemm_bt<1><<<gg, 256, 0, stream>>>(queries, WqT, bq, qw, 1);
    gemm_bt<1><<<gg, 256, 0, stream>>>(keys,    WkT, bk, kw, 1);
    gemm_bt<1><<<gg, 256, 0, stream>>>(values,  WvT, bv, vtw, 2);

    attn_kernel<<<dim3(32, 16, 4), 256, 0, stream>>>(qw, kw, vtw, ow);

    gemm_bt<0><<<gg, 256, 0, stream>>>(ow, WoT, bo, d_out, 0);  // fp32 out
}